// Round 1
// 477.061 us; speedup vs baseline: 1.1196x; 1.1196x over previous
//
#include <hip/hip_runtime.h>

#define N_NODES 100000
#define N_EDGES 1600000
#define DIM 128

#define BK_BITS 7
#define BK_NODES 128
#define NBK ((N_NODES + BK_NODES - 1) / BK_NODES)   // 782
#define BCAP 2688                 // mean 2046/bucket, sd ~45 -> 14 sigma

typedef __attribute__((ext_vector_type(8))) short bf16x8;
typedef __attribute__((ext_vector_type(4))) float f32x4;

__device__ inline unsigned short f2bf(float f) {
    unsigned u = __builtin_bit_cast(unsigned, f);
    return (unsigned short)((u + 0x7FFFu + ((u >> 16) & 1u)) >> 16);   // RNE
}
__device__ inline float bf2f(unsigned short u) {
    unsigned v = ((unsigned)u) << 16;
    return __builtin_bit_cast(float, v);
}

// ===========================================================================
// x -> bf16 (vectorized), once per call
// ===========================================================================
__global__ __launch_bounds__(256) void xcvt_k(const float* __restrict__ x,
                                              unsigned short* __restrict__ xb)
{
    int i = (blockIdx.x * 256 + threadIdx.x) * 4;
    if (i >= N_NODES * DIM) return;
    float4 v = *(const float4*)(x + i);
    unsigned short o[4] = {f2bf(v.x), f2bf(v.y), f2bf(v.z), f2bf(v.w)};
    xb[i] = o[0]; xb[i+1] = o[1]; xb[i+2] = o[2]; xb[i+3] = o[3];
}

// ===========================================================================
// Block-aggregated bucket fill: 8192 edges/block. LDS histogram over 782
// buckets -> ONE global atomic per (block,bucket) range reservation ->
// LDS-cursor scatter.
// ===========================================================================
__global__ __launch_bounds__(512) void bfill2_k(const int* __restrict__ ei,
                                                int* __restrict__ bcursor,
                                                int* __restrict__ bbuf)
{
    __shared__ int hist[NBK];
    __shared__ int cur[NBK];
    const int t = threadIdx.x;
    const int e0 = blockIdx.x * 8192;

    for (int b = t; b < NBK; b += 512) hist[b] = 0;
    __syncthreads();
    #pragma unroll
    for (int i = 0; i < 16; ++i) {
        int e = e0 + i * 512 + t;
        if (e < N_EDGES) atomicAdd(&hist[ei[N_EDGES + e] >> BK_BITS], 1);
    }
    __syncthreads();
    for (int b = t; b < NBK; b += 512) {
        int h = hist[b];
        cur[b] = h ? atomicAdd(bcursor + b, h) : 0;
    }
    __syncthreads();
    #pragma unroll
    for (int i = 0; i < 16; ++i) {
        int e = e0 + i * 512 + t;
        if (e < N_EDGES) {
            int src = ei[e];
            int dst = ei[N_EDGES + e];
            int b = dst >> BK_BITS;
            int pos = atomicAdd(&cur[b], 1);
            if (pos < BCAP) bbuf[b * BCAP + pos] = ((dst & (BK_NODES - 1)) << 17) | src;
        }
    }
}

// ===========================================================================
// ONE-TIME counting sort per bucket (was redone inside every agg call).
// Sorts bbuf in place into per-node runs of plain src indices, and emits
// global CSR metadata nstart[node] / ndeg[node]. In-place is safe: all
// global reads land in wreg before the LDS scatter; the global writeback
// (coalesced, from LDS elist) happens after a barrier.
// ===========================================================================
__global__ __launch_bounds__(256) void bsort_k(const int* __restrict__ bcursor,
                                               int* __restrict__ bbuf,
                                               int* __restrict__ nstart,
                                               int* __restrict__ ndeg)
{
    __shared__ int elist[BCAP];
    __shared__ int bins[BK_NODES];
    __shared__ int startp[BK_NODES];
    __shared__ int cur[BK_NODES];
    __shared__ int scanb[BK_NODES];

    const int t = threadIdx.x;
    const int b = blockIdx.x;

    if (t < BK_NODES) bins[t] = 0;
    __syncthreads();

    int n = bcursor[b];
    if (n > BCAP) n = BCAP;
    int* bp = bbuf + b * BCAP;

    int wreg[(BCAP + 255) / 256];                 // 11
    const int nIter = (n + 255) >> 8;
    #pragma unroll
    for (int i = 0; i < (BCAP + 255) / 256; ++i) wreg[i] = -1;
    for (int i = 0; i < nIter; ++i) {
        int idx = t + (i << 8);
        if (idx < n) {
            int word = bp[idx];
            wreg[i] = word;
            atomicAdd(&bins[word >> 17], 1);
        }
    }
    __syncthreads();

    if (t < BK_NODES) scanb[t] = bins[t];
    __syncthreads();
    #pragma unroll
    for (int off = 1; off < BK_NODES; off <<= 1) {
        int add = (t >= off && t < BK_NODES) ? scanb[t - off] : 0;
        __syncthreads();
        if (t < BK_NODES) scanb[t] += add;
        __syncthreads();
    }
    if (t < BK_NODES) {
        startp[t] = scanb[t] - bins[t];
        cur[t] = scanb[t] - bins[t];
        int node = b * BK_NODES + t;
        if (node < N_NODES) {
            nstart[node] = b * BCAP + (scanb[t] - bins[t]);
            ndeg[node] = bins[t];
        }
    }
    __syncthreads();

    for (int i = 0; i < nIter; ++i) {
        int word = wreg[i];
        if (word >= 0) {
            int dl = word >> 17;
            int pos = atomicAdd(&cur[dl], 1);
            elist[pos] = word & 0x1FFFF;
        }
    }
    __syncthreads();

    for (int i = t; i < n; i += 256) bp[i] = elist[i];      // coalesced writeback
}

// ===========================================================================
// CSR mean-aggregation gather (bf16): no LDS, no atomics, no syncs.
// Quarter-wave (16 lanes) per node, bf16x8 (16B) loads, 4-edge unroll.
// Grid-stride so occupancy is capped only by waves/CU.
// ab[n] = bf16( x[n] + mean over in-neighbors ), fp32 accumulate.
// ===========================================================================
__global__ __launch_bounds__(512) void agg_csr_k(const unsigned short* __restrict__ xb,
                                                 const int* __restrict__ elist,
                                                 const int* __restrict__ nstart,
                                                 const int* __restrict__ ndeg,
                                                 unsigned short* __restrict__ ab)
{
    const int t = threadIdx.x;
    const int wv = t >> 6;              // wave in block: 0..7
    const int lane = t & 63;
    const int qw = lane >> 4;           // quarter-wave 0..3 -> node sub-index
    const int c  = lane & 15;           // col chunk: cols c*8 .. c*8+7

    const int g  = blockIdx.x * 8 + wv; // global wave id
    const int NW = gridDim.x * 8;       // total waves

    for (int n0 = g * 4; n0 < N_NODES; n0 += NW * 4) {
        int node = n0 + qw;
        bool valid = node < N_NODES;
        int beg = valid ? nstart[node] : 0;
        int deg = valid ? ndeg[node] : 0;
        int end = beg + deg;

        float a[8];
        #pragma unroll
        for (int u = 0; u < 8; ++u) a[u] = 0.f;

        int e = beg;
        for (; e + 4 <= end; e += 4) {
            int s0 = elist[e], s1 = elist[e + 1], s2 = elist[e + 2], s3 = elist[e + 3];
            bf16x8 v0 = *(const bf16x8*)(xb + s0 * DIM + c * 8);
            bf16x8 v1 = *(const bf16x8*)(xb + s1 * DIM + c * 8);
            bf16x8 v2 = *(const bf16x8*)(xb + s2 * DIM + c * 8);
            bf16x8 v3 = *(const bf16x8*)(xb + s3 * DIM + c * 8);
            #pragma unroll
            for (int u = 0; u < 8; ++u)
                a[u] += (bf2f((unsigned short)v0[u]) + bf2f((unsigned short)v1[u]))
                      + (bf2f((unsigned short)v2[u]) + bf2f((unsigned short)v3[u]));
        }
        for (; e < end; ++e) {
            int s0 = elist[e];
            bf16x8 v0 = *(const bf16x8*)(xb + s0 * DIM + c * 8);
            #pragma unroll
            for (int u = 0; u < 8; ++u) a[u] += bf2f((unsigned short)v0[u]);
        }

        if (valid) {
            float inv = 1.0f / fmaxf((float)deg, 1.0f);
            bf16x8 xv = *(const bf16x8*)(xb + node * DIM + c * 8);
            bf16x8 o;
            #pragma unroll
            for (int u = 0; u < 8; ++u)
                o[u] = (short)f2bf(bf2f((unsigned short)xv[u]) + a[u] * inv);
            *(bf16x8*)(ab + node * DIM + c * 8) = o;
        }
    }
}

// ===========================================================================
// Weight transpose+convert: Wt[n*128+k] = bf16(W[k*128+n]).
// ===========================================================================
__global__ __launch_bounds__(256) void wcvt_k(const float* __restrict__ W,
                                              unsigned short* __restrict__ Wt)
{
    int id = blockIdx.x * 256 + threadIdx.x;      // 16384
    int n = id >> 7, k = id & 127;
    Wt[n * DIM + k] = f2bf(W[k * DIM + n]);
}

// ===========================================================================
// MFMA GEMM1: h1(fp32) = A(bf16) @ W1 + b1, + fused BN column stats.
// ===========================================================================
__global__ __launch_bounds__(256) void gemm1_mfma_k(
    const unsigned short* __restrict__ ab, float* __restrict__ h1,
    const unsigned short* __restrict__ Wt, const float* __restrict__ bias,
    float* __restrict__ colsum, float* __restrict__ colsq)
{
    __shared__ unsigned short Alds[128 * 136];
    __shared__ unsigned short Wlds[128 * 136];
    __shared__ float cstat[256];

    const int t = threadIdx.x;
    const int row0 = blockIdx.x * 128;
    if (t < 256) cstat[t] = 0.f;

    for (int i = t; i < 2048; i += 256) {
        int r = i >> 4, seg = i & 15;
        int gr = row0 + r;
        bf16x8 o = (gr < N_NODES) ? *(const bf16x8*)(ab + gr * DIM + seg * 8)
                                  : (bf16x8)(short)0;
        *(bf16x8*)(Alds + r * 136 + seg * 8) = o;
        *(bf16x8*)(Wlds + r * 136 + seg * 8) = *(const bf16x8*)(Wt + r * DIM + seg * 8);
    }
    __syncthreads();

    const int w = t >> 6, lane = t & 63;
    const int m = lane & 15, q = lane >> 4;

    f32x4 acc[2][8];
    #pragma unroll
    for (int i = 0; i < 2; ++i)
        #pragma unroll
        for (int ct = 0; ct < 8; ++ct) acc[i][ct] = (f32x4)0.f;

    #pragma unroll
    for (int kb = 0; kb < DIM; kb += 32) {
        bf16x8 af0 = *(bf16x8*)(Alds + ((w * 2 + 0) * 16 + m) * 136 + kb + q * 8);
        bf16x8 af1 = *(bf16x8*)(Alds + ((w * 2 + 1) * 16 + m) * 136 + kb + q * 8);
        #pragma unroll
        for (int ct = 0; ct < 8; ++ct) {
            bf16x8 bf = *(bf16x8*)(Wlds + (ct * 16 + m) * 136 + kb + q * 8);
            acc[0][ct] = __builtin_amdgcn_mfma_f32_16x16x32_bf16(af0, bf, acc[0][ct], 0, 0, 0);
            acc[1][ct] = __builtin_amdgcn_mfma_f32_16x16x32_bf16(af1, bf, acc[1][ct], 0, 0, 0);
        }
    }

    #pragma unroll
    for (int ct = 0; ct < 8; ++ct) {
        int col = ct * 16 + m;
        float bb = bias[col];
        float ps = 0.f, pq = 0.f;
        #pragma unroll
        for (int i = 0; i < 2; ++i) {
            int rbase = row0 + (w * 2 + i) * 16 + q * 4;
            #pragma unroll
            for (int r = 0; r < 4; ++r) {
                int gr = rbase + r;
                if (gr < N_NODES) {
                    float v = acc[i][ct][r] + bb;
                    h1[gr * DIM + col] = v;
                    ps += v; pq += v * v;
                }
            }
        }
        atomicAdd(&cstat[col], ps);
        atomicAdd(&cstat[128 + col], pq);
    }
    __syncthreads();
    if (t < 128) {
        atomicAdd(colsum + t, cstat[t]);
        atomicAdd(colsq + t, cstat[128 + t]);
    }
}

__global__ void bnstats_k(const float* __restrict__ colsum, const float* __restrict__ colsq,
                          const float* __restrict__ gamma, const float* __restrict__ beta,
                          float* __restrict__ scale, float* __restrict__ shift)
{
    int j = threadIdx.x;
    const float inv_n = 1.0f / (float)N_NODES;
    float mu = colsum[j] * inv_n;
    float var = colsq[j] * inv_n - mu * mu;   // biased variance (torch BN)
    float sc = gamma[j] * rsqrtf(var + 1e-5f);
    scale[j] = sc;
    shift[j] = beta[j] - mu * sc;
}

// ===========================================================================
// MFMA GEMM2: t = relu(h1*scale+shift); r = t @ W2 + b2.
// mode 1: write bf16 relu(r) -> xbout (inter-layer activation)
// mode 0: write fp32 r -> outf (final output)
// ===========================================================================
__global__ __launch_bounds__(256) void gemm2_mfma_k(
    const float* __restrict__ h1, const float* __restrict__ scale, const float* __restrict__ shift,
    const unsigned short* __restrict__ Wt, const float* __restrict__ bias,
    float* __restrict__ outf, unsigned short* __restrict__ xbout, int mode)
{
    __shared__ unsigned short Alds[128 * 136];
    __shared__ unsigned short Wlds[128 * 136];
    __shared__ float ssc[256];

    const int t = threadIdx.x;
    const int row0 = blockIdx.x * 128;
    if (t < 128) { ssc[t] = scale[t]; ssc[128 + t] = shift[t]; }
    __syncthreads();

    for (int i = t; i < 2048; i += 256) {
        int r = i >> 4, seg = i & 15;
        int gr = row0 + r;
        bf16x8 o;
        if (gr < N_NODES) {
            const float* p = h1 + gr * DIM + seg * 8;
            float4 v0 = *(const float4*)p;
            float4 v1 = *(const float4*)(p + 4);
            int cb = seg * 8;
            float f[8] = {v0.x, v0.y, v0.z, v0.w, v1.x, v1.y, v1.z, v1.w};
            #pragma unroll
            for (int u = 0; u < 8; ++u) {
                float v = fmaxf(f[u] * ssc[cb + u] + ssc[128 + cb + u], 0.f);
                o[u] = (short)f2bf(v);
            }
        } else {
            o = (bf16x8)(short)0;
        }
        *(bf16x8*)(Alds + r * 136 + seg * 8) = o;
        *(bf16x8*)(Wlds + r * 136 + seg * 8) = *(const bf16x8*)(Wt + r * DIM + seg * 8);
    }
    __syncthreads();

    const int w = t >> 6, lane = t & 63;
    const int m = lane & 15, q = lane >> 4;

    f32x4 acc[2][8];
    #pragma unroll
    for (int i = 0; i < 2; ++i)
        #pragma unroll
        for (int ct = 0; ct < 8; ++ct) acc[i][ct] = (f32x4)0.f;

    #pragma unroll
    for (int kb = 0; kb < DIM; kb += 32) {
        bf16x8 af0 = *(bf16x8*)(Alds + ((w * 2 + 0) * 16 + m) * 136 + kb + q * 8);
        bf16x8 af1 = *(bf16x8*)(Alds + ((w * 2 + 1) * 16 + m) * 136 + kb + q * 8);
        #pragma unroll
        for (int ct = 0; ct < 8; ++ct) {
            bf16x8 bf = *(bf16x8*)(Wlds + (ct * 16 + m) * 136 + kb + q * 8);
            acc[0][ct] = __builtin_amdgcn_mfma_f32_16x16x32_bf16(af0, bf, acc[0][ct], 0, 0, 0);
            acc[1][ct] = __builtin_amdgcn_mfma_f32_16x16x32_bf16(af1, bf, acc[1][ct], 0, 0, 0);
        }
    }

    #pragma unroll
    for (int ct = 0; ct < 8; ++ct) {
        int col = ct * 16 + m;
        float bb = bias[col];
        #pragma unroll
        for (int i = 0; i < 2; ++i) {
            int rbase = row0 + (w * 2 + i) * 16 + q * 4;
            #pragma unroll
            for (int r = 0; r < 4; ++r) {
                int gr = rbase + r;
                if (gr < N_NODES) {
                    float v = acc[i][ct][r] + bb;
                    if (mode) xbout[gr * DIM + col] = f2bf(fmaxf(v, 0.f));
                    else      outf[gr * DIM + col] = v;
                }
            }
        }
    }
}

// ---------------------------------------------------------------------------
// Workspace (float units):
//   h1     @ 0          : 12,800,000 fp32
//   colsum @ 12,800,000 : +128 colsq, +256 scale, +384 shift (512)
//   xb     @ 12,800,512 : 12.8M ushort (6.4M floats)  [x_bf16 / interlayer]
//   ab     @ 19,200,512 : 12.8M ushort (6.4M floats)  [agg output]
//   ints   @ 25,600,512 : bbuf[NBK*BCAP=2,102,016], bcursor[782],
//                         nstart[100,000], ndeg[100,000]
//   ushorts after      : Wt x4 (16384 each)
// Total ≈ 112 MB.
// ---------------------------------------------------------------------------
extern "C" void kernel_launch(void* const* d_in, const int* in_sizes, int n_in,
                              void* d_out, int out_size, void* d_ws, size_t ws_size,
                              hipStream_t stream)
{
    const float* x    = (const float*)d_in[0];
    const int*   ei   = (const int*)d_in[1];
    const float* W1_0 = (const float*)d_in[2];
    const float* b1_0 = (const float*)d_in[3];
    const float* g_0  = (const float*)d_in[4];
    const float* be_0 = (const float*)d_in[5];
    const float* W2_0 = (const float*)d_in[6];
    const float* b2_0 = (const float*)d_in[7];
    const float* W1_1 = (const float*)d_in[8];
    const float* b1_1 = (const float*)d_in[9];
    const float* g_1  = (const float*)d_in[10];
    const float* be_1 = (const float*)d_in[11];
    const float* W2_1 = (const float*)d_in[12];
    const float* b2_1 = (const float*)d_in[13];
    float* out = (float*)d_out;
    float* ws  = (float*)d_ws;

    float* h1     = ws;
    float* colsum = ws + 12800000;
    float* colsq  = colsum + 128;
    float* scale  = colsum + 256;
    float* shift  = colsum + 384;
    unsigned short* xb = (unsigned short*)(ws + 12800512);
    unsigned short* ab = (unsigned short*)(ws + 19200512);
    int* ibase    = (int*)(ws + 25600512);
    int* bbuf     = ibase;
    int* bcursor  = ibase + NBK * BCAP;
    int* nstart   = bcursor + NBK + 2;
    int* ndeg     = nstart + N_NODES;
    unsigned short* wt10 = (unsigned short*)(ndeg + N_NODES);
    unsigned short* wt20 = wt10 + 16384;
    unsigned short* wt11 = wt10 + 32768;
    unsigned short* wt21 = wt10 + 49152;

    dim3 blk(256);
    int mfma_blocks = (N_NODES + 127) / 128;           // 782
    int fill_blocks = (N_EDGES + 8191) / 8192;         // 196

    // ---- one-time converts + bucket build + one-time counting sort ----
    xcvt_k<<<(N_NODES * DIM / 4 + 255) / 256, blk, 0, stream>>>(x, xb);
    wcvt_k<<<64, blk, 0, stream>>>(W1_0, wt10);
    wcvt_k<<<64, blk, 0, stream>>>(W2_0, wt20);
    wcvt_k<<<64, blk, 0, stream>>>(W1_1, wt11);
    wcvt_k<<<64, blk, 0, stream>>>(W2_1, wt21);
    hipMemsetAsync(bcursor, 0, NBK * sizeof(int), stream);
    bfill2_k<<<fill_blocks, 512, 0, stream>>>(ei, bcursor, bbuf);
    bsort_k<<<NBK, blk, 0, stream>>>(bcursor, bbuf, nstart, ndeg);

    // ---- layer 0 ----
    hipMemsetAsync(colsum, 0, 256 * sizeof(float), stream);
    agg_csr_k<<<1024, 512, 0, stream>>>(xb, bbuf, nstart, ndeg, ab);
    gemm1_mfma_k<<<mfma_blocks, blk, 0, stream>>>(ab, h1, wt10, b1_0, colsum, colsq);
    bnstats_k<<<1, 128, 0, stream>>>(colsum, colsq, g_0, be_0, scale, shift);
    gemm2_mfma_k<<<mfma_blocks, blk, 0, stream>>>(h1, scale, shift, wt20, b2_0, nullptr, xb, 1);

    // ---- layer 1 ----
    hipMemsetAsync(colsum, 0, 256 * sizeof(float), stream);
    agg_csr_k<<<1024, 512, 0, stream>>>(xb, bbuf, nstart, ndeg, ab);
    gemm1_mfma_k<<<mfma_blocks, blk, 0, stream>>>(ab, h1, wt11, b1_1, colsum, colsq);
    bnstats_k<<<1, 128, 0, stream>>>(colsum, colsq, g_1, be_1, scale, shift);
    gemm2_mfma_k<<<mfma_blocks, blk, 0, stream>>>(h1, scale, shift, wt21, b2_1, out, nullptr, 0);
}

// Round 2
// 453.709 us; speedup vs baseline: 1.1772x; 1.0515x over previous
//
#include <hip/hip_runtime.h>

#define N_NODES 100000
#define N_EDGES 1600000
#define DIM 128

#define BK_BITS 7
#define BK_NODES 128
#define NBK ((N_NODES + BK_NODES - 1) / BK_NODES)   // 782
#define BCAP 2688                 // mean 2046/bucket, sd ~45 -> 14 sigma

typedef __attribute__((ext_vector_type(8))) short bf16x8;
typedef __attribute__((ext_vector_type(4))) float f32x4;

__device__ inline unsigned short f2bf(float f) {
    unsigned u = __builtin_bit_cast(unsigned, f);
    return (unsigned short)((u + 0x7FFFu + ((u >> 16) & 1u)) >> 16);   // RNE
}
__device__ inline float bf2f(unsigned short u) {
    unsigned v = ((unsigned)u) << 16;
    return __builtin_bit_cast(float, v);
}

// ===========================================================================
// x -> bf16 (vectorized), once per call
// ===========================================================================
__global__ __launch_bounds__(256) void xcvt_k(const float* __restrict__ x,
                                              unsigned short* __restrict__ xb)
{
    int i = (blockIdx.x * 256 + threadIdx.x) * 4;
    if (i >= N_NODES * DIM) return;
    float4 v = *(const float4*)(x + i);
    unsigned short o[4] = {f2bf(v.x), f2bf(v.y), f2bf(v.z), f2bf(v.w)};
    xb[i] = o[0]; xb[i+1] = o[1]; xb[i+2] = o[2]; xb[i+3] = o[3];
}

// ===========================================================================
// Block-aggregated bucket fill: 8192 edges/block. LDS histogram over 782
// buckets -> ONE global atomic per (block,bucket) range reservation ->
// LDS-cursor scatter.
// ===========================================================================
__global__ __launch_bounds__(512) void bfill2_k(const int* __restrict__ ei,
                                                int* __restrict__ bcursor,
                                                int* __restrict__ bbuf)
{
    __shared__ int hist[NBK];
    __shared__ int cur[NBK];
    const int t = threadIdx.x;
    const int e0 = blockIdx.x * 8192;

    for (int b = t; b < NBK; b += 512) hist[b] = 0;
    __syncthreads();
    #pragma unroll
    for (int i = 0; i < 16; ++i) {
        int e = e0 + i * 512 + t;
        if (e < N_EDGES) atomicAdd(&hist[ei[N_EDGES + e] >> BK_BITS], 1);
    }
    __syncthreads();
    for (int b = t; b < NBK; b += 512) {
        int h = hist[b];
        cur[b] = h ? atomicAdd(bcursor + b, h) : 0;
    }
    __syncthreads();
    #pragma unroll
    for (int i = 0; i < 16; ++i) {
        int e = e0 + i * 512 + t;
        if (e < N_EDGES) {
            int src = ei[e];
            int dst = ei[N_EDGES + e];
            int b = dst >> BK_BITS;
            int pos = atomicAdd(&cur[b], 1);
            if (pos < BCAP) bbuf[b * BCAP + pos] = ((dst & (BK_NODES - 1)) << 17) | src;
        }
    }
}

// ===========================================================================
// ONE-TIME counting sort per bucket. Sorts bbuf in place into per-node runs
// of plain src indices, and emits global CSR metadata nstart/ndeg.
// ===========================================================================
__global__ __launch_bounds__(256) void bsort_k(const int* __restrict__ bcursor,
                                               int* __restrict__ bbuf,
                                               int* __restrict__ nstart,
                                               int* __restrict__ ndeg)
{
    __shared__ int elist[BCAP];
    __shared__ int bins[BK_NODES];
    __shared__ int cur[BK_NODES];
    __shared__ int scanb[BK_NODES];

    const int t = threadIdx.x;
    const int b = blockIdx.x;

    if (t < BK_NODES) bins[t] = 0;
    __syncthreads();

    int n = bcursor[b];
    if (n > BCAP) n = BCAP;
    int* bp = bbuf + b * BCAP;

    int wreg[(BCAP + 255) / 256];                 // 11
    const int nIter = (n + 255) >> 8;
    #pragma unroll
    for (int i = 0; i < (BCAP + 255) / 256; ++i) wreg[i] = -1;
    for (int i = 0; i < nIter; ++i) {
        int idx = t + (i << 8);
        if (idx < n) {
            int word = bp[idx];
            wreg[i] = word;
            atomicAdd(&bins[word >> 17], 1);
        }
    }
    __syncthreads();

    if (t < BK_NODES) scanb[t] = bins[t];
    __syncthreads();
    #pragma unroll
    for (int off = 1; off < BK_NODES; off <<= 1) {
        int add = (t >= off && t < BK_NODES) ? scanb[t - off] : 0;
        __syncthreads();
        if (t < BK_NODES) scanb[t] += add;
        __syncthreads();
    }
    if (t < BK_NODES) {
        cur[t] = scanb[t] - bins[t];
        int node = b * BK_NODES + t;
        if (node < N_NODES) {
            nstart[node] = b * BCAP + (scanb[t] - bins[t]);
            ndeg[node] = bins[t];
        }
    }
    __syncthreads();

    for (int i = 0; i < nIter; ++i) {
        int word = wreg[i];
        if (word >= 0) {
            int dl = word >> 17;
            int pos = atomicAdd(&cur[dl], 1);
            elist[pos] = word & 0x1FFFF;
        }
    }
    __syncthreads();

    for (int i = t; i < n; i += 256) bp[i] = elist[i];      // coalesced writeback
}

// ===========================================================================
// CSR mean-aggregation gather (bf16): no LDS, no atomics, no syncs.
// 2 nodes per wave per iteration; each node is split across TWO 16-lane
// groups (half the edge list each), combined with one shfl_xor(16) round.
// Finer work granularity cuts the static tail (50000 units / 8192 waves
// = 6.1 iters vs 3.05 before).
// ab[n] = bf16( x[n] + mean over in-neighbors ), fp32 accumulate.
// ===========================================================================
__global__ __launch_bounds__(512) void agg_csr_k(const unsigned short* __restrict__ xb,
                                                 const int* __restrict__ elist,
                                                 const int* __restrict__ nstart,
                                                 const int* __restrict__ ndeg,
                                                 unsigned short* __restrict__ ab)
{
    const int t = threadIdx.x;
    const int wv = t >> 6;              // wave in block: 0..7
    const int lane = t & 63;
    const int qw = lane >> 4;           // 0..3
    const int c  = lane & 15;           // col chunk: cols c*8 .. c*8+7
    const int sub = qw & 1;             // which half of the edge list
    const int nn  = qw >> 1;            // node within the pair

    const int g  = blockIdx.x * 8 + wv; // global wave id
    const int NW = gridDim.x * 8;       // total waves

    for (int n0 = g * 2; n0 < N_NODES; n0 += NW * 2) {
        int node = n0 + nn;
        bool valid = node < N_NODES;
        int beg = 0, deg = 0;
        if (valid) { beg = nstart[node]; deg = ndeg[node]; }
        int mid = beg + ((deg + 1) >> 1);
        int end = beg + deg;
        int lo = sub ? mid : beg;
        int hi = sub ? end : mid;

        float a[8];
        #pragma unroll
        for (int u = 0; u < 8; ++u) a[u] = 0.f;

        int e = lo;
        for (; e + 4 <= hi; e += 4) {
            int s0 = elist[e], s1 = elist[e + 1], s2 = elist[e + 2], s3 = elist[e + 3];
            bf16x8 v0 = *(const bf16x8*)(xb + s0 * DIM + c * 8);
            bf16x8 v1 = *(const bf16x8*)(xb + s1 * DIM + c * 8);
            bf16x8 v2 = *(const bf16x8*)(xb + s2 * DIM + c * 8);
            bf16x8 v3 = *(const bf16x8*)(xb + s3 * DIM + c * 8);
            #pragma unroll
            for (int u = 0; u < 8; ++u)
                a[u] += (bf2f((unsigned short)v0[u]) + bf2f((unsigned short)v1[u]))
                      + (bf2f((unsigned short)v2[u]) + bf2f((unsigned short)v3[u]));
        }
        for (; e < hi; ++e) {
            int s0 = elist[e];
            bf16x8 v0 = *(const bf16x8*)(xb + s0 * DIM + c * 8);
            #pragma unroll
            for (int u = 0; u < 8; ++u) a[u] += bf2f((unsigned short)v0[u]);
        }

        // combine the two half-sums for this node (lanes qw0<->qw1, qw2<->qw3)
        #pragma unroll
        for (int u = 0; u < 8; ++u) a[u] += __shfl_xor(a[u], 16, 64);

        if (valid && sub == 0) {
            float inv = 1.0f / fmaxf((float)deg, 1.0f);
            bf16x8 xv = *(const bf16x8*)(xb + node * DIM + c * 8);
            bf16x8 o;
            #pragma unroll
            for (int u = 0; u < 8; ++u)
                o[u] = (short)f2bf(bf2f((unsigned short)xv[u]) + a[u] * inv);
            *(bf16x8*)(ab + node * DIM + c * 8) = o;
        }
    }
}

// ===========================================================================
// Weight transpose+convert: Wt[n*128+k] = bf16(W[k*128+n]).
// ===========================================================================
__global__ __launch_bounds__(256) void wcvt_k(const float* __restrict__ W,
                                              unsigned short* __restrict__ Wt)
{
    int id = blockIdx.x * 256 + threadIdx.x;      // 16384
    int n = id >> 7, k = id & 127;
    Wt[n * DIM + k] = f2bf(W[k * DIM + n]);
}

// ===========================================================================
// Stats-only GEMM1: MFMA A(bf16)@W1 + b1, accumulate BN colsum/colsq ONLY.
// No h1 store -> h1 intermediate is eliminated from global memory entirely.
// ===========================================================================
__global__ __launch_bounds__(256) void gemm1_stats_k(
    const unsigned short* __restrict__ ab,
    const unsigned short* __restrict__ Wt, const float* __restrict__ bias,
    float* __restrict__ colsum, float* __restrict__ colsq)
{
    __shared__ unsigned short Alds[128 * 136];
    __shared__ unsigned short Wlds[128 * 136];
    __shared__ float cstat[256];

    const int t = threadIdx.x;
    const int row0 = blockIdx.x * 128;
    if (t < 256) cstat[t] = 0.f;

    for (int i = t; i < 2048; i += 256) {
        int r = i >> 4, seg = i & 15;
        int gr = row0 + r;
        bf16x8 o = (gr < N_NODES) ? *(const bf16x8*)(ab + gr * DIM + seg * 8)
                                  : (bf16x8)(short)0;
        *(bf16x8*)(Alds + r * 136 + seg * 8) = o;
        *(bf16x8*)(Wlds + r * 136 + seg * 8) = *(const bf16x8*)(Wt + r * DIM + seg * 8);
    }
    __syncthreads();

    const int w = t >> 6, lane = t & 63;
    const int m = lane & 15, q = lane >> 4;

    f32x4 acc[2][8];
    #pragma unroll
    for (int i = 0; i < 2; ++i)
        #pragma unroll
        for (int ct = 0; ct < 8; ++ct) acc[i][ct] = (f32x4)0.f;

    #pragma unroll
    for (int kb = 0; kb < DIM; kb += 32) {
        bf16x8 af0 = *(bf16x8*)(Alds + ((w * 2 + 0) * 16 + m) * 136 + kb + q * 8);
        bf16x8 af1 = *(bf16x8*)(Alds + ((w * 2 + 1) * 16 + m) * 136 + kb + q * 8);
        #pragma unroll
        for (int ct = 0; ct < 8; ++ct) {
            bf16x8 bf = *(bf16x8*)(Wlds + (ct * 16 + m) * 136 + kb + q * 8);
            acc[0][ct] = __builtin_amdgcn_mfma_f32_16x16x32_bf16(af0, bf, acc[0][ct], 0, 0, 0);
            acc[1][ct] = __builtin_amdgcn_mfma_f32_16x16x32_bf16(af1, bf, acc[1][ct], 0, 0, 0);
        }
    }

    #pragma unroll
    for (int ct = 0; ct < 8; ++ct) {
        int col = ct * 16 + m;
        float bb = bias[col];
        float ps = 0.f, pq = 0.f;
        #pragma unroll
        for (int i = 0; i < 2; ++i) {
            int rbase = row0 + (w * 2 + i) * 16 + q * 4;
            #pragma unroll
            for (int r = 0; r < 4; ++r) {
                int gr = rbase + r;
                if (gr < N_NODES) {
                    float v = acc[i][ct][r] + bb;
                    ps += v; pq += v * v;
                }
            }
        }
        atomicAdd(&cstat[col], ps);
        atomicAdd(&cstat[128 + col], pq);
    }
    __syncthreads();
    if (t < 128) {
        atomicAdd(colsum + t, cstat[t]);
        atomicAdd(colsq + t, cstat[128 + t]);
    }
}

__global__ void bnstats_k(const float* __restrict__ colsum, const float* __restrict__ colsq,
                          const float* __restrict__ gamma, const float* __restrict__ beta,
                          float* __restrict__ scale, float* __restrict__ shift)
{
    int j = threadIdx.x;
    const float inv_n = 1.0f / (float)N_NODES;
    float mu = colsum[j] * inv_n;
    float var = colsq[j] * inv_n - mu * mu;   // biased variance (torch BN)
    float sc = gamma[j] * rsqrtf(var + 1e-5f);
    scale[j] = sc;
    shift[j] = beta[j] - mu * sc;
}

// ===========================================================================
// Fused MLP: acc1 = A@W1; t = relu((acc1+b1)*scale+shift) -> bf16 via LDS;
// acc2 = t@W2 + b2. One kernel, no h1 in global memory.
// mode 1: write bf16 relu(out) -> xbout (inter-layer activation)
// mode 0: write fp32 out -> outf (final output)
// Garbage rows (gr >= N_NODES) stay row-local through both GEMMs and are
// simply not stored.
// ===========================================================================
__global__ __launch_bounds__(256) void fused_mlp_k(
    const unsigned short* __restrict__ ab,
    const float* __restrict__ scale, const float* __restrict__ shift,
    const unsigned short* __restrict__ Wt1, const float* __restrict__ b1,
    const unsigned short* __restrict__ Wt2, const float* __restrict__ b2,
    float* __restrict__ outf, unsigned short* __restrict__ xbout, int mode)
{
    __shared__ unsigned short Alds[128 * 136];
    __shared__ unsigned short Wlds[128 * 136];
    __shared__ float ssc[384];    // scale | shift | b1

    const int t = threadIdx.x;
    const int row0 = blockIdx.x * 128;
    if (t < 128) { ssc[t] = scale[t]; ssc[128 + t] = shift[t]; ssc[256 + t] = b1[t]; }

    for (int i = t; i < 2048; i += 256) {
        int r = i >> 4, seg = i & 15;
        int gr = row0 + r;
        bf16x8 o = (gr < N_NODES) ? *(const bf16x8*)(ab + gr * DIM + seg * 8)
                                  : (bf16x8)(short)0;
        *(bf16x8*)(Alds + r * 136 + seg * 8) = o;
        *(bf16x8*)(Wlds + r * 136 + seg * 8) = *(const bf16x8*)(Wt1 + r * DIM + seg * 8);
    }
    __syncthreads();

    const int w = t >> 6, lane = t & 63;
    const int m = lane & 15, q = lane >> 4;

    f32x4 acc[2][8];
    #pragma unroll
    for (int i = 0; i < 2; ++i)
        #pragma unroll
        for (int ct = 0; ct < 8; ++ct) acc[i][ct] = (f32x4)0.f;

    #pragma unroll
    for (int kb = 0; kb < DIM; kb += 32) {
        bf16x8 af0 = *(bf16x8*)(Alds + ((w * 2 + 0) * 16 + m) * 136 + kb + q * 8);
        bf16x8 af1 = *(bf16x8*)(Alds + ((w * 2 + 1) * 16 + m) * 136 + kb + q * 8);
        #pragma unroll
        for (int ct = 0; ct < 8; ++ct) {
            bf16x8 bf = *(bf16x8*)(Wlds + (ct * 16 + m) * 136 + kb + q * 8);
            acc[0][ct] = __builtin_amdgcn_mfma_f32_16x16x32_bf16(af0, bf, acc[0][ct], 0, 0, 0);
            acc[1][ct] = __builtin_amdgcn_mfma_f32_16x16x32_bf16(af1, bf, acc[1][ct], 0, 0, 0);
        }
    }

    __syncthreads();   // all waves done reading Alds (A) and Wlds (W1)

    // BN + ReLU epilogue: scatter t into Alds row-major (bf16), and
    // restage Wlds with W2.
    #pragma unroll
    for (int ct = 0; ct < 8; ++ct) {
        int col = ct * 16 + m;
        float sc = ssc[col], sh = ssc[128 + col], bb = ssc[256 + col];
        #pragma unroll
        for (int i = 0; i < 2; ++i) {
            int rrow = (w * 2 + i) * 16 + q * 4;
            #pragma unroll
            for (int r = 0; r < 4; ++r) {
                float v = acc[i][ct][r] + bb;
                float tt = fmaxf(v * sc + sh, 0.f);
                Alds[(rrow + r) * 136 + col] = f2bf(tt);
            }
        }
    }
    for (int i = t; i < 2048; i += 256) {
        int r = i >> 4, seg = i & 15;
        *(bf16x8*)(Wlds + r * 136 + seg * 8) = *(const bf16x8*)(Wt2 + r * DIM + seg * 8);
    }
    __syncthreads();

    #pragma unroll
    for (int i = 0; i < 2; ++i)
        #pragma unroll
        for (int ct = 0; ct < 8; ++ct) acc[i][ct] = (f32x4)0.f;

    #pragma unroll
    for (int kb = 0; kb < DIM; kb += 32) {
        bf16x8 af0 = *(bf16x8*)(Alds + ((w * 2 + 0) * 16 + m) * 136 + kb + q * 8);
        bf16x8 af1 = *(bf16x8*)(Alds + ((w * 2 + 1) * 16 + m) * 136 + kb + q * 8);
        #pragma unroll
        for (int ct = 0; ct < 8; ++ct) {
            bf16x8 bf = *(bf16x8*)(Wlds + (ct * 16 + m) * 136 + kb + q * 8);
            acc[0][ct] = __builtin_amdgcn_mfma_f32_16x16x32_bf16(af0, bf, acc[0][ct], 0, 0, 0);
            acc[1][ct] = __builtin_amdgcn_mfma_f32_16x16x32_bf16(af1, bf, acc[1][ct], 0, 0, 0);
        }
    }

    #pragma unroll
    for (int ct = 0; ct < 8; ++ct) {
        int col = ct * 16 + m;
        float bb = b2[col];
        #pragma unroll
        for (int i = 0; i < 2; ++i) {
            int rbase = row0 + (w * 2 + i) * 16 + q * 4;
            #pragma unroll
            for (int r = 0; r < 4; ++r) {
                int gr = rbase + r;
                if (gr < N_NODES) {
                    float v = acc[i][ct][r] + bb;
                    if (mode) xbout[gr * DIM + col] = f2bf(fmaxf(v, 0.f));
                    else      outf[gr * DIM + col] = v;
                }
            }
        }
    }
}

// ---------------------------------------------------------------------------
// Workspace (float units):
//   colsum @ 12,800,000 : +128 colsq, +256 scale, +384 shift (512)
//   xb     @ 12,800,512 : 12.8M ushort (6.4M floats)  [x_bf16 / interlayer]
//   ab     @ 19,200,512 : 12.8M ushort (6.4M floats)  [agg output]
//   ints   @ 25,600,512 : bbuf[NBK*BCAP=2,102,016], bcursor[782],
//                         nstart[100,000], ndeg[100,000]
//   ushorts after      : Wt x4 (16384 each)
// (h1 region @0 now unused)
// ---------------------------------------------------------------------------
extern "C" void kernel_launch(void* const* d_in, const int* in_sizes, int n_in,
                              void* d_out, int out_size, void* d_ws, size_t ws_size,
                              hipStream_t stream)
{
    const float* x    = (const float*)d_in[0];
    const int*   ei   = (const int*)d_in[1];
    const float* W1_0 = (const float*)d_in[2];
    const float* b1_0 = (const float*)d_in[3];
    const float* g_0  = (const float*)d_in[4];
    const float* be_0 = (const float*)d_in[5];
    const float* W2_0 = (const float*)d_in[6];
    const float* b2_0 = (const float*)d_in[7];
    const float* W1_1 = (const float*)d_in[8];
    const float* b1_1 = (const float*)d_in[9];
    const float* g_1  = (const float*)d_in[10];
    const float* be_1 = (const float*)d_in[11];
    const float* W2_1 = (const float*)d_in[12];
    const float* b2_1 = (const float*)d_in[13];
    float* out = (float*)d_out;
    float* ws  = (float*)d_ws;

    float* colsum = ws + 12800000;
    float* colsq  = colsum + 128;
    float* scale  = colsum + 256;
    float* shift  = colsum + 384;
    unsigned short* xb = (unsigned short*)(ws + 12800512);
    unsigned short* ab = (unsigned short*)(ws + 19200512);
    int* ibase    = (int*)(ws + 25600512);
    int* bbuf     = ibase;
    int* bcursor  = ibase + NBK * BCAP;
    int* nstart   = bcursor + NBK + 2;
    int* ndeg     = nstart + N_NODES;
    unsigned short* wt10 = (unsigned short*)(ndeg + N_NODES);
    unsigned short* wt20 = wt10 + 16384;
    unsigned short* wt11 = wt10 + 32768;
    unsigned short* wt21 = wt10 + 49152;

    dim3 blk(256);
    int mfma_blocks = (N_NODES + 127) / 128;           // 782
    int fill_blocks = (N_EDGES + 8191) / 8192;         // 196

    // ---- one-time converts + bucket build + one-time counting sort ----
    xcvt_k<<<(N_NODES * DIM / 4 + 255) / 256, blk, 0, stream>>>(x, xb);
    wcvt_k<<<64, blk, 0, stream>>>(W1_0, wt10);
    wcvt_k<<<64, blk, 0, stream>>>(W2_0, wt20);
    wcvt_k<<<64, blk, 0, stream>>>(W1_1, wt11);
    wcvt_k<<<64, blk, 0, stream>>>(W2_1, wt21);
    hipMemsetAsync(bcursor, 0, NBK * sizeof(int), stream);
    bfill2_k<<<fill_blocks, 512, 0, stream>>>(ei, bcursor, bbuf);
    bsort_k<<<NBK, blk, 0, stream>>>(bcursor, bbuf, nstart, ndeg);

    // ---- layer 0 ----
    hipMemsetAsync(colsum, 0, 256 * sizeof(float), stream);
    agg_csr_k<<<1024, 512, 0, stream>>>(xb, bbuf, nstart, ndeg, ab);
    gemm1_stats_k<<<mfma_blocks, blk, 0, stream>>>(ab, wt10, b1_0, colsum, colsq);
    bnstats_k<<<1, 128, 0, stream>>>(colsum, colsq, g_0, be_0, scale, shift);
    fused_mlp_k<<<mfma_blocks, blk, 0, stream>>>(ab, scale, shift, wt10, b1_0,
                                                 wt20, b2_0, nullptr, xb, 1);

    // ---- layer 1 ----
    hipMemsetAsync(colsum, 0, 256 * sizeof(float), stream);
    agg_csr_k<<<1024, 512, 0, stream>>>(xb, bbuf, nstart, ndeg, ab);
    gemm1_stats_k<<<mfma_blocks, blk, 0, stream>>>(ab, wt11, b1_1, colsum, colsq);
    bnstats_k<<<1, 128, 0, stream>>>(colsum, colsq, g_1, be_1, scale, shift);
    fused_mlp_k<<<mfma_blocks, blk, 0, stream>>>(ab, scale, shift, wt11, b1_1,
                                                 wt21, b2_1, out, nullptr, 0);
}

// Round 4
// 434.776 us; speedup vs baseline: 1.2284x; 1.0435x over previous
//
#include <hip/hip_runtime.h>

#define N_NODES 100000
#define N_EDGES 1600000
#define DIM 128

#define BK_BITS 7
#define BK_NODES 128
#define NBK ((N_NODES + BK_NODES - 1) / BK_NODES)   // 782
#define BCAP 2688                 // mean 2046/bucket, sd ~45 -> 14 sigma

typedef __attribute__((ext_vector_type(8))) short bf16x8;
typedef __attribute__((ext_vector_type(4))) float f32x4;

__device__ inline unsigned short f2bf(float f) {
    unsigned u = __builtin_bit_cast(unsigned, f);
    return (unsigned short)((u + 0x7FFFu + ((u >> 16) & 1u)) >> 16);   // RNE
}
__device__ inline float bf2f(unsigned short u) {
    unsigned v = ((unsigned)u) << 16;
    return __builtin_bit_cast(float, v);
}

// Direct global->LDS 16B DMA. LDS dest = wave-uniform base + lane*16.
__device__ __forceinline__ void gl16(const void* g, void* l) {
    __builtin_amdgcn_global_load_lds(
        (const __attribute__((address_space(1))) void*)g,
        (__attribute__((address_space(3))) void*)l, 16, 0, 0);
}

// Stage a 128-row x 256B tile: linear LDS dest, INVERSE-swizzled global src.
// Swizzle: byte-in-row ^= (row&7)<<4  (keeps ds_read_b128 conflict-free).
__device__ __forceinline__ void stage_tile(const void* gbase, void* lds, int t) {
    const int wvS = t >> 6, lnS = t & 63;
    #pragma unroll
    for (int k = 0; k < 8; ++k) {
        int chunk = wvS * 8 + k;                 // 0..31 (1KB each)
        int r = chunk * 4 + (lnS >> 4);          // row 0..127
        int gb = ((lnS & 15) * 16) ^ ((r & 7) << 4);
        gl16((const char*)gbase + (size_t)r * 256 + gb,
             (char*)lds + chunk * 1024);
    }
}

// Swizzled bf16x8 fragment read (matching the staging swizzle).
__device__ __forceinline__ bf16x8 frag8(const unsigned short* lds, int row, int bo) {
    return *(const bf16x8*)((const char*)lds + row * 256 + (bo ^ ((row & 7) << 4)));
}

// ===========================================================================
// x -> bf16 (vectorized), once per call
// ===========================================================================
__global__ __launch_bounds__(256) void xcvt_k(const float* __restrict__ x,
                                              unsigned short* __restrict__ xb)
{
    int i = (blockIdx.x * 256 + threadIdx.x) * 4;
    if (i >= N_NODES * DIM) return;
    float4 v = *(const float4*)(x + i);
    unsigned short o[4] = {f2bf(v.x), f2bf(v.y), f2bf(v.z), f2bf(v.w)};
    xb[i] = o[0]; xb[i+1] = o[1]; xb[i+2] = o[2]; xb[i+3] = o[3];
}

// ===========================================================================
// Block-aggregated bucket fill: 8192 edges/block. LDS histogram over 782
// buckets -> ONE global atomic per (block,bucket) range reservation ->
// LDS-cursor scatter.
// ===========================================================================
__global__ __launch_bounds__(512) void bfill2_k(const int* __restrict__ ei,
                                                int* __restrict__ bcursor,
                                                int* __restrict__ bbuf)
{
    __shared__ int hist[NBK];
    __shared__ int cur[NBK];
    const int t = threadIdx.x;
    const int e0 = blockIdx.x * 8192;

    for (int b = t; b < NBK; b += 512) hist[b] = 0;
    __syncthreads();
    #pragma unroll
    for (int i = 0; i < 16; ++i) {
        int e = e0 + i * 512 + t;
        if (e < N_EDGES) atomicAdd(&hist[ei[N_EDGES + e] >> BK_BITS], 1);
    }
    __syncthreads();
    for (int b = t; b < NBK; b += 512) {
        int h = hist[b];
        cur[b] = h ? atomicAdd(bcursor + b, h) : 0;
    }
    __syncthreads();
    #pragma unroll
    for (int i = 0; i < 16; ++i) {
        int e = e0 + i * 512 + t;
        if (e < N_EDGES) {
            int src = ei[e];
            int dst = ei[N_EDGES + e];
            int b = dst >> BK_BITS;
            int pos = atomicAdd(&cur[b], 1);
            if (pos < BCAP) bbuf[b * BCAP + pos] = ((dst & (BK_NODES - 1)) << 17) | src;
        }
    }
}

// ===========================================================================
// ONE-TIME counting sort per bucket. Sorts bbuf in place into per-node runs
// of plain src indices, and emits global CSR metadata nstart/ndeg.
// ===========================================================================
__global__ __launch_bounds__(256) void bsort_k(const int* __restrict__ bcursor,
                                               int* __restrict__ bbuf,
                                               int* __restrict__ nstart,
                                               int* __restrict__ ndeg)
{
    __shared__ int elist[BCAP];
    __shared__ int bins[BK_NODES];
    __shared__ int cur[BK_NODES];
    __shared__ int scanb[BK_NODES];

    const int t = threadIdx.x;
    const int b = blockIdx.x;

    if (t < BK_NODES) bins[t] = 0;
    __syncthreads();

    int n = bcursor[b];
    if (n > BCAP) n = BCAP;
    int* bp = bbuf + b * BCAP;

    int wreg[(BCAP + 255) / 256];                 // 11
    const int nIter = (n + 255) >> 8;
    #pragma unroll
    for (int i = 0; i < (BCAP + 255) / 256; ++i) wreg[i] = -1;
    for (int i = 0; i < nIter; ++i) {
        int idx = t + (i << 8);
        if (idx < n) {
            int word = bp[idx];
            wreg[i] = word;
            atomicAdd(&bins[word >> 17], 1);
        }
    }
    __syncthreads();

    if (t < BK_NODES) scanb[t] = bins[t];
    __syncthreads();
    #pragma unroll
    for (int off = 1; off < BK_NODES; off <<= 1) {
        int add = (t >= off && t < BK_NODES) ? scanb[t - off] : 0;
        __syncthreads();
        if (t < BK_NODES) scanb[t] += add;
        __syncthreads();
    }
    if (t < BK_NODES) {
        cur[t] = scanb[t] - bins[t];
        int node = b * BK_NODES + t;
        if (node < N_NODES) {
            nstart[node] = b * BCAP + (scanb[t] - bins[t]);
            ndeg[node] = bins[t];
        }
    }
    __syncthreads();

    for (int i = 0; i < nIter; ++i) {
        int word = wreg[i];
        if (word >= 0) {
            int dl = word >> 17;
            int pos = atomicAdd(&cur[dl], 1);
            elist[pos] = word & 0x1FFFF;
        }
    }
    __syncthreads();

    for (int i = t; i < n; i += 256) bp[i] = elist[i];      // coalesced writeback
}

// ===========================================================================
// CSR mean-aggregation gather (bf16): no LDS, no atomics, no syncs.
// 2 nodes per wave per iteration; each node split across two 16-lane groups
// (half the edge list each), combined with one shfl_xor(16) round.
// ab[n] = bf16( x[n] + mean over in-neighbors ), fp32 accumulate.
// ===========================================================================
__global__ __launch_bounds__(512) void agg_csr_k(const unsigned short* __restrict__ xb,
                                                 const int* __restrict__ elist,
                                                 const int* __restrict__ nstart,
                                                 const int* __restrict__ ndeg,
                                                 unsigned short* __restrict__ ab)
{
    const int t = threadIdx.x;
    const int wv = t >> 6;              // wave in block: 0..7
    const int lane = t & 63;
    const int qw = lane >> 4;           // 0..3
    const int c  = lane & 15;           // col chunk: cols c*8 .. c*8+7
    const int sub = qw & 1;             // which half of the edge list
    const int nn  = qw >> 1;            // node within the pair

    const int g  = blockIdx.x * 8 + wv; // global wave id
    const int NW = gridDim.x * 8;       // total waves

    for (int n0 = g * 2; n0 < N_NODES; n0 += NW * 2) {
        int node = n0 + nn;
        bool valid = node < N_NODES;
        int beg = 0, deg = 0;
        if (valid) { beg = nstart[node]; deg = ndeg[node]; }
        int mid = beg + ((deg + 1) >> 1);
        int end = beg + deg;
        int lo = sub ? mid : beg;
        int hi = sub ? end : mid;

        float a[8];
        #pragma unroll
        for (int u = 0; u < 8; ++u) a[u] = 0.f;

        int e = lo;
        for (; e + 4 <= hi; e += 4) {
            int s0 = elist[e], s1 = elist[e + 1], s2 = elist[e + 2], s3 = elist[e + 3];
            bf16x8 v0 = *(const bf16x8*)(xb + s0 * DIM + c * 8);
            bf16x8 v1 = *(const bf16x8*)(xb + s1 * DIM + c * 8);
            bf16x8 v2 = *(const bf16x8*)(xb + s2 * DIM + c * 8);
            bf16x8 v3 = *(const bf16x8*)(xb + s3 * DIM + c * 8);
            #pragma unroll
            for (int u = 0; u < 8; ++u)
                a[u] += (bf2f((unsigned short)v0[u]) + bf2f((unsigned short)v1[u]))
                      + (bf2f((unsigned short)v2[u]) + bf2f((unsigned short)v3[u]));
        }
        for (; e < hi; ++e) {
            int s0 = elist[e];
            bf16x8 v0 = *(const bf16x8*)(xb + s0 * DIM + c * 8);
            #pragma unroll
            for (int u = 0; u < 8; ++u) a[u] += bf2f((unsigned short)v0[u]);
        }

        // combine the two half-sums for this node (lanes qw0<->qw1, qw2<->qw3)
        #pragma unroll
        for (int u = 0; u < 8; ++u) a[u] += __shfl_xor(a[u], 16, 64);

        if (valid && sub == 0) {
            float inv = 1.0f / fmaxf((float)deg, 1.0f);
            bf16x8 xv = *(const bf16x8*)(xb + node * DIM + c * 8);
            bf16x8 o;
            #pragma unroll
            for (int u = 0; u < 8; ++u)
                o[u] = (short)f2bf(bf2f((unsigned short)xv[u]) + a[u] * inv);
            *(bf16x8*)(ab + node * DIM + c * 8) = o;
        }
    }
}

// ===========================================================================
// All 4 weight transposes+converts in ONE launch: Wt[n*128+k] = bf16(W[k*128+n])
// ===========================================================================
__global__ __launch_bounds__(256) void wcvt4_k(const float* __restrict__ Wa,
                                               const float* __restrict__ Wb,
                                               const float* __restrict__ Wc,
                                               const float* __restrict__ Wd,
                                               unsigned short* __restrict__ wt)
{
    int id = blockIdx.x * 256 + threadIdx.x;      // 65536
    int which = id >> 14, rem = id & 16383;
    const float* W = (which == 0) ? Wa : (which == 1) ? Wb : (which == 2) ? Wc : Wd;
    int n = rem >> 7, k = rem & 127;
    wt[which * 16384 + n * DIM + k] = f2bf(W[k * DIM + n]);
}

// ===========================================================================
// Stats-only GEMM1: MFMA A(bf16)@W1 + b1, accumulate BN colsum/colsq ONLY.
// Staging via global_load_lds width=16 (linear LDS + swizzled source).
// Out-of-range tail rows read adjacent workspace (garbage) -- row-local
// through the MFMA and guarded out of the stats.
// ===========================================================================
__global__ __launch_bounds__(256) void gemm1_stats_k(
    const unsigned short* __restrict__ ab,
    const unsigned short* __restrict__ Wt, const float* __restrict__ bias,
    float* __restrict__ colsum, float* __restrict__ colsq)
{
    __shared__ unsigned short Alds[128 * 128];
    __shared__ unsigned short Wlds[128 * 128];
    __shared__ float cstat[256];

    const int t = threadIdx.x;
    const int row0 = blockIdx.x * 128;
    if (t < 256) cstat[t] = 0.f;

    stage_tile((const char*)ab + (size_t)row0 * 256, Alds, t);
    stage_tile(Wt, Wlds, t);
    __syncthreads();                 // compiler drains vmcnt before barrier

    const int w = t >> 6, lane = t & 63;
    const int m = lane & 15, q = lane >> 4;

    f32x4 acc[2][8];
    #pragma unroll
    for (int i = 0; i < 2; ++i)
        #pragma unroll
        for (int ct = 0; ct < 8; ++ct) acc[i][ct] = (f32x4)0.f;

    #pragma unroll
    for (int kb = 0; kb < 4; ++kb) {
        int bo = kb * 64 + q * 16;
        bf16x8 af0 = frag8(Alds, (w * 2 + 0) * 16 + m, bo);
        bf16x8 af1 = frag8(Alds, (w * 2 + 1) * 16 + m, bo);
        #pragma unroll
        for (int ct = 0; ct < 8; ++ct) {
            bf16x8 bfv = frag8(Wlds, ct * 16 + m, bo);
            acc[0][ct] = __builtin_amdgcn_mfma_f32_16x16x32_bf16(af0, bfv, acc[0][ct], 0, 0, 0);
            acc[1][ct] = __builtin_amdgcn_mfma_f32_16x16x32_bf16(af1, bfv, acc[1][ct], 0, 0, 0);
        }
    }

    #pragma unroll
    for (int ct = 0; ct < 8; ++ct) {
        int col = ct * 16 + m;
        float bb = bias[col];
        float ps = 0.f, pq = 0.f;
        #pragma unroll
        for (int i = 0; i < 2; ++i) {
            int rbase = row0 + (w * 2 + i) * 16 + q * 4;
            #pragma unroll
            for (int r = 0; r < 4; ++r) {
                if (rbase + r < N_NODES) {
                    float v = acc[i][ct][r] + bb;
                    ps += v; pq += v * v;
                }
            }
        }
        atomicAdd(&cstat[col], ps);
        atomicAdd(&cstat[128 + col], pq);
    }
    __syncthreads();
    if (t < 128) {
        atomicAdd(colsum + t, cstat[t]);
        atomicAdd(colsq + t, cstat[128 + t]);
    }
}

__global__ void bnstats_k(const float* __restrict__ colsum, const float* __restrict__ colsq,
                          const float* __restrict__ gamma, const float* __restrict__ beta,
                          float* __restrict__ scale, float* __restrict__ shift)
{
    int j = threadIdx.x;
    const float inv_n = 1.0f / (float)N_NODES;
    float mu = colsum[j] * inv_n;
    float var = colsq[j] * inv_n - mu * mu;   // biased variance (torch BN)
    float sc = gamma[j] * rsqrtf(var + 1e-5f);
    scale[j] = sc;
    shift[j] = beta[j] - mu * sc;
}

// ===========================================================================
// Fused MLP: acc1 = A@W1; t = relu((acc1+b1)*scale+shift) -> bf16 via LDS;
// acc2 = t@W2 + b2. Staging via global_load_lds (swizzled).
// mode 1: write bf16 relu(out) -> xbout ; mode 0: write fp32 out -> outf
// ===========================================================================
__global__ __launch_bounds__(256) void fused_mlp_k(
    const unsigned short* __restrict__ ab,
    const float* __restrict__ scale, const float* __restrict__ shift,
    const unsigned short* __restrict__ Wt1, const float* __restrict__ b1,
    const unsigned short* __restrict__ Wt2, const float* __restrict__ b2,
    float* __restrict__ outf, unsigned short* __restrict__ xbout, int mode)
{
    __shared__ unsigned short Alds[128 * 128];
    __shared__ unsigned short Wlds[128 * 128];
    __shared__ float ssc[384];    // scale | shift | b1

    const int t = threadIdx.x;
    const int row0 = blockIdx.x * 128;
    if (t < 128) { ssc[t] = scale[t]; ssc[128 + t] = shift[t]; ssc[256 + t] = b1[t]; }

    stage_tile((const char*)ab + (size_t)row0 * 256, Alds, t);
    stage_tile(Wt1, Wlds, t);
    __syncthreads();

    const int w = t >> 6, lane = t & 63;
    const int m = lane & 15, q = lane >> 4;

    f32x4 acc[2][8];
    #pragma unroll
    for (int i = 0; i < 2; ++i)
        #pragma unroll
        for (int ct = 0; ct < 8; ++ct) acc[i][ct] = (f32x4)0.f;

    #pragma unroll
    for (int kb = 0; kb < 4; ++kb) {
        int bo = kb * 64 + q * 16;
        bf16x8 af0 = frag8(Alds, (w * 2 + 0) * 16 + m, bo);
        bf16x8 af1 = frag8(Alds, (w * 2 + 1) * 16 + m, bo);
        #pragma unroll
        for (int ct = 0; ct < 8; ++ct) {
            bf16x8 bfv = frag8(Wlds, ct * 16 + m, bo);
            acc[0][ct] = __builtin_amdgcn_mfma_f32_16x16x32_bf16(af0, bfv, acc[0][ct], 0, 0, 0);
            acc[1][ct] = __builtin_amdgcn_mfma_f32_16x16x32_bf16(af1, bfv, acc[1][ct], 0, 0, 0);
        }
    }

    __syncthreads();   // all waves done reading Alds (A) and Wlds (W1)

    // BN + ReLU epilogue: scatter t into Alds (swizzled bf16), restage W2.
    #pragma unroll
    for (int ct = 0; ct < 8; ++ct) {
        int col = ct * 16 + m;
        float sc = ssc[col], sh = ssc[128 + col], bb = ssc[256 + col];
        #pragma unroll
        for (int i = 0; i < 2; ++i) {
            int rr0 = (w * 2 + i) * 16 + q * 4;
            #pragma unroll
            for (int r = 0; r < 4; ++r) {
                int row = rr0 + r;
                float v = acc[i][ct][r] + bb;
                float tt = fmaxf(v * sc + sh, 0.f);
                *(unsigned short*)((char*)Alds + row * 256 +
                                   ((col * 2) ^ ((row & 7) << 4))) = f2bf(tt);
            }
        }
    }
    stage_tile(Wt2, Wlds, t);
    __syncthreads();

    #pragma unroll
    for (int i = 0; i < 2; ++i)
        #pragma unroll
        for (int ct = 0; ct < 8; ++ct) acc[i][ct] = (f32x4)0.f;

    #pragma unroll
    for (int kb = 0; kb < 4; ++kb) {
        int bo = kb * 64 + q * 16;
        bf16x8 af0 = frag8(Alds, (w * 2 + 0) * 16 + m, bo);
        bf16x8 af1 = frag8(Alds, (w * 2 + 1) * 16 + m, bo);
        #pragma unroll
        for (int ct = 0; ct < 8; ++ct) {
            bf16x8 bfv = frag8(Wlds, ct * 16 + m, bo);
            acc[0][ct] = __builtin_amdgcn_mfma_f32_16x16x32_bf16(af0, bfv, acc[0][ct], 0, 0, 0);
            acc[1][ct] = __builtin_amdgcn_mfma_f32_16x16x32_bf16(af1, bfv, acc[1][ct], 0, 0, 0);
        }
    }

    #pragma unroll
    for (int ct = 0; ct < 8; ++ct) {
        int col = ct * 16 + m;
        float bb = b2[col];
        #pragma unroll
        for (int i = 0; i < 2; ++i) {
            int rbase = row0 + (w * 2 + i) * 16 + q * 4;
            #pragma unroll
            for (int r = 0; r < 4; ++r) {
                int gr = rbase + r;
                if (gr < N_NODES) {
                    float v = acc[i][ct][r] + bb;
                    if (mode) xbout[gr * DIM + col] = f2bf(fmaxf(v, 0.f));
                    else      outf[gr * DIM + col] = v;
                }
            }
        }
    }
}

// ---------------------------------------------------------------------------
// Workspace (float units):
//   colsum @ 12,800,000 : +128 colsq, +256 scale, +384 shift (512)
//   xb     @ 12,800,512 : 12.8M ushort (6.4M floats)  [x_bf16 / interlayer]
//   ab     @ 19,200,512 : 12.8M ushort (6.4M floats)  [agg output]
//   ints   @ 25,600,512 : bbuf[NBK*BCAP=2,102,016], bcursor[782],
//                         nstart[100,000], ndeg[100,000]
//   ushorts after      : Wt x4 (16384 each, 16B-aligned)
// ---------------------------------------------------------------------------
extern "C" void kernel_launch(void* const* d_in, const int* in_sizes, int n_in,
                              void* d_out, int out_size, void* d_ws, size_t ws_size,
                              hipStream_t stream)
{
    const float* x    = (const float*)d_in[0];
    const int*   ei   = (const int*)d_in[1];
    const float* W1_0 = (const float*)d_in[2];
    const float* b1_0 = (const float*)d_in[3];
    const float* g_0  = (const float*)d_in[4];
    const float* be_0 = (const float*)d_in[5];
    const float* W2_0 = (const float*)d_in[6];
    const float* b2_0 = (const float*)d_in[7];
    const float* W1_1 = (const float*)d_in[8];
    const float* b1_1 = (const float*)d_in[9];
    const float* g_1  = (const float*)d_in[10];
    const float* be_1 = (const float*)d_in[11];
    const float* W2_1 = (const float*)d_in[12];
    const float* b2_1 = (const float*)d_in[13];
    float* out = (float*)d_out;
    float* ws  = (float*)d_ws;

    float* colsum = ws + 12800000;
    float* colsq  = colsum + 128;
    float* scale  = colsum + 256;
    float* shift  = colsum + 384;
    unsigned short* xb = (unsigned short*)(ws + 12800512);
    unsigned short* ab = (unsigned short*)(ws + 19200512);
    int* ibase    = (int*)(ws + 25600512);
    int* bbuf     = ibase;
    int* bcursor  = ibase + NBK * BCAP;
    int* nstart   = bcursor + NBK + 2;
    int* ndeg     = nstart + N_NODES;
    unsigned short* wt10 = (unsigned short*)(ndeg + N_NODES);
    unsigned short* wt20 = wt10 + 16384;
    unsigned short* wt11 = wt10 + 32768;
    unsigned short* wt21 = wt10 + 49152;

    dim3 blk(256);
    int mfma_blocks = (N_NODES + 127) / 128;           // 782
    int fill_blocks = (N_EDGES + 8191) / 8192;         // 196

    // ---- one-time converts + bucket build + one-time counting sort ----
    xcvt_k<<<(N_NODES * DIM / 4 + 255) / 256, blk, 0, stream>>>(x, xb);
    wcvt4_k<<<256, blk, 0, stream>>>(W1_0, W2_0, W1_1, W2_1, wt10);
    hipMemsetAsync(bcursor, 0, NBK * sizeof(int), stream);
    bfill2_k<<<fill_blocks, 512, 0, stream>>>(ei, bcursor, bbuf);
    bsort_k<<<NBK, blk, 0, stream>>>(bcursor, bbuf, nstart, ndeg);

    // ---- layer 0 ----
    hipMemsetAsync(colsum, 0, 256 * sizeof(float), stream);
    agg_csr_k<<<1024, 512, 0, stream>>>(xb, bbuf, nstart, ndeg, ab);
    gemm1_stats_k<<<mfma_blocks, blk, 0, stream>>>(ab, wt10, b1_0, colsum, colsq);
    bnstats_k<<<1, 128, 0, stream>>>(colsum, colsq, g_0, be_0, scale, shift);
    fused_mlp_k<<<mfma_blocks, blk, 0, stream>>>(ab, scale, shift, wt10, b1_0,
                                                 wt20, b2_0, nullptr, xb, 1);

    // ---- layer 1 ----
    hipMemsetAsync(colsum, 0, 256 * sizeof(float), stream);
    agg_csr_k<<<1024, 512, 0, stream>>>(xb, bbuf, nstart, ndeg, ab);
    gemm1_stats_k<<<mfma_blocks, blk, 0, stream>>>(ab, wt11, b1_1, colsum, colsq);
    bnstats_k<<<1, 128, 0, stream>>>(colsum, colsq, g_1, be_1, scale, shift);
    fused_mlp_k<<<mfma_blocks, blk, 0, stream>>>(ab, scale, shift, wt11, b1_1,
                                                 wt21, b2_1, out, nullptr, 0);
}